// Round 1
// 538.199 us; speedup vs baseline: 1.4580x; 1.4580x over previous
//
#include <hip/hip_runtime.h>
#include <math.h>

#define B_ 4
#define L_ 1024
#define D_ 1024
#define H_ 16
#define DH_ 64
#define M_ (B_*L_)   // 4096 rows

typedef _Float16 half8 __attribute__((ext_vector_type(8)));
typedef _Float16 half4 __attribute__((ext_vector_type(4)));
typedef float f32x4 __attribute__((ext_vector_type(4)));

#define MFMA16(a,b,c) __builtin_amdgcn_mfma_f32_16x16x32_f16(a, b, c, 0, 0, 0)

// ---------------- split kernels: fp32 -> scaled fp16 hi/lo pairs ----------------
// x scaled by 16, W scaled by 512 -> product scale 8192, undone in GEMM epilogue.
// Keeps lo-parts in fp16 normal range; combined representation error ~2^-22
// (<= current fp32 re-association error, so top-k tie behavior is unchanged).
__global__ __launch_bounds__(256) void split_x(const float* __restrict__ x,
                                               _Float16* __restrict__ xh,
                                               _Float16* __restrict__ xl) {
  const int i = blockIdx.x * 256 + threadIdx.x;   // 4 floats per thread
  float4 v = ((const float4*)x)[i];
  const float a0 = v.x * 16.f, a1 = v.y * 16.f, a2 = v.z * 16.f, a3 = v.w * 16.f;
  const _Float16 h0 = (_Float16)a0, h1 = (_Float16)a1, h2 = (_Float16)a2, h3 = (_Float16)a3;
  half4 hv, lv;
  hv[0] = h0; hv[1] = h1; hv[2] = h2; hv[3] = h3;
  lv[0] = (_Float16)(a0 - (float)h0);
  lv[1] = (_Float16)(a1 - (float)h1);
  lv[2] = (_Float16)(a2 - (float)h2);
  lv[3] = (_Float16)(a3 - (float)h3);
  ((half4*)xh)[i] = hv;
  ((half4*)xl)[i] = lv;
}

// W[k][n] -> transposed split Wh[n][k], Wl[n][k] (scale 512), via LDS tile.
__global__ __launch_bounds__(256) void split_wt(const float* __restrict__ W,
                                                _Float16* __restrict__ Wh,
                                                _Float16* __restrict__ Wl) {
  __shared__ float tile[64][65];
  const int t = threadIdx.x;
  const int tk = blockIdx.x & 15;
  const int tn = blockIdx.x >> 4;
  const int kr = t >> 2, ns = (t & 3) * 16;
  const float* src = W + (size_t)(tk * 64 + kr) * D_ + tn * 64 + ns;
  float4 v0 = ((const float4*)src)[0];
  float4 v1 = ((const float4*)src)[1];
  float4 v2 = ((const float4*)src)[2];
  float4 v3 = ((const float4*)src)[3];
  tile[ns + 0][kr] = v0.x;  tile[ns + 1][kr] = v0.y;  tile[ns + 2][kr] = v0.z;  tile[ns + 3][kr] = v0.w;
  tile[ns + 4][kr] = v1.x;  tile[ns + 5][kr] = v1.y;  tile[ns + 6][kr] = v1.z;  tile[ns + 7][kr] = v1.w;
  tile[ns + 8][kr] = v2.x;  tile[ns + 9][kr] = v2.y;  tile[ns + 10][kr] = v2.z; tile[ns + 11][kr] = v2.w;
  tile[ns + 12][kr] = v3.x; tile[ns + 13][kr] = v3.y; tile[ns + 14][kr] = v3.z; tile[ns + 15][kr] = v3.w;
  __syncthreads();
  const int nr = t >> 2, ks = (t & 3) * 16;
  const float* tr = &tile[nr][ks];
  half8 hv0, hv1, lv0, lv1;
#pragma unroll
  for (int i = 0; i < 8; i++) {
    const float s0 = tr[i] * 512.f;
    const float s1 = tr[i + 8] * 512.f;
    const _Float16 h0 = (_Float16)s0, h1 = (_Float16)s1;
    hv0[i] = h0; hv1[i] = h1;
    lv0[i] = (_Float16)(s0 - (float)h0);
    lv1[i] = (_Float16)(s1 - (float)h1);
  }
  _Float16* dh = Wh + (size_t)(tn * 64 + nr) * D_ + tk * 64 + ks;
  _Float16* dl = Wl + (size_t)(tn * 64 + nr) * D_ + tk * 64 + ks;
  *(half8*)dh = hv0; *(half8*)(dh + 8) = hv1;
  *(half8*)dl = lv0; *(half8*)(dl + 8) = lv1;
}

// ---------------- fp16x3 MFMA GEMM: C = (Ah+Al)(Bh+Bl)/8192 + bias ----------------
// 128x128 tile, BK=32, 4 waves (2x2), each wave 64x64 = 4x4 frags of 16x16x32.
// A and B both stored row-major-in-k ([row][k]); B pre-transposed by split_wt.
// LDS: [row][k] with 16B-slot XOR swizzle slot^((row>>1)&3): source-side swizzled
// (4 consecutive lanes permute within one 64B segment -> still fully coalesced),
// reads land 2-way on banks (free). 3 MFMAs per frag-pair into one accumulator.
__device__ __forceinline__ void gemm_f16x3_body(
    const _Float16* __restrict__ Ah, const _Float16* __restrict__ Al,
    const _Float16* __restrict__ Bh, const _Float16* __restrict__ Bl,
    const float* __restrict__ bias, float* __restrict__ C) {
  __shared__ __align__(16) _Float16 sA[2][2][128][32];  // [buf][hi/lo][row][k] 16KB*2
  __shared__ __align__(16) _Float16 sB[2][2][128][32];
  const int t = threadIdx.x;
  const int lane = t & 63;
  const int wid = t >> 6;
  const int bm = blockIdx.y * 128;
  const int bn = blockIdx.x * 128;

  // staging: chunk c (16B = 8 halves): m = c>>2, phys slot sp = c&3,
  // source slot sl = sp ^ ((m>>1)&3). Thread t owns chunks t and t+256.
  const int m0 = t >> 2, sp0 = t & 3;
  const int sl0 = sp0 ^ ((m0 >> 1) & 3);
  const int m1 = m0 + 64;               // ((m1>>1)&3) == ((m0>>1)&3) -> same sl0
  const _Float16* gA0h = Ah + (size_t)(bm + m0) * D_ + sl0 * 8;
  const _Float16* gA1h = Ah + (size_t)(bm + m1) * D_ + sl0 * 8;
  const _Float16* gA0l = Al + (size_t)(bm + m0) * D_ + sl0 * 8;
  const _Float16* gA1l = Al + (size_t)(bm + m1) * D_ + sl0 * 8;
  const _Float16* gB0h = Bh + (size_t)(bn + m0) * D_ + sl0 * 8;
  const _Float16* gB1h = Bh + (size_t)(bn + m1) * D_ + sl0 * 8;
  const _Float16* gB0l = Bl + (size_t)(bn + m0) * D_ + sl0 * 8;
  const _Float16* gB1l = Bl + (size_t)(bn + m1) * D_ + sl0 * 8;

  // prologue: stage K-tile 0 into buf 0
  half8 rA0h = *(const half8*)(gA0h);
  half8 rA1h = *(const half8*)(gA1h);
  half8 rA0l = *(const half8*)(gA0l);
  half8 rA1l = *(const half8*)(gA1l);
  half8 rB0h = *(const half8*)(gB0h);
  half8 rB1h = *(const half8*)(gB1h);
  half8 rB0l = *(const half8*)(gB0l);
  half8 rB1l = *(const half8*)(gB1l);
  *(half8*)&sA[0][0][m0][sp0 * 8] = rA0h;
  *(half8*)&sA[0][0][m1][sp0 * 8] = rA1h;
  *(half8*)&sA[0][1][m0][sp0 * 8] = rA0l;
  *(half8*)&sA[0][1][m1][sp0 * 8] = rA1l;
  *(half8*)&sB[0][0][m0][sp0 * 8] = rB0h;
  *(half8*)&sB[0][0][m1][sp0 * 8] = rB1h;
  *(half8*)&sB[0][1][m0][sp0 * 8] = rB0l;
  *(half8*)&sB[0][1][m1][sp0 * 8] = rB1l;
  __syncthreads();

  f32x4 acc[4][4];
#pragma unroll
  for (int i = 0; i < 4; i++)
#pragma unroll
    for (int j = 0; j < 4; j++) acc[i][j] = {0.f, 0.f, 0.f, 0.f};

  const int wr = wid >> 1, wc = wid & 1;
  const int l15 = lane & 15;
  // logical k-slot (lane>>4) lives at phys slot (lane>>4)^((row>>1)&3);
  // rows differ by multiples of 16 so the XOR term depends only on l15.
  const int soff = ((lane >> 4) ^ ((l15 >> 1) & 3)) * 8;

  int p = 0;
  for (int k0 = 0; k0 < 1024; k0 += 32) {
    const bool more = (k0 + 32) < 1024;
    if (more) {
      const int kk = k0 + 32;
      rA0h = *(const half8*)(gA0h + kk);
      rA1h = *(const half8*)(gA1h + kk);
      rA0l = *(const half8*)(gA0l + kk);
      rA1l = *(const half8*)(gA1l + kk);
      rB0h = *(const half8*)(gB0h + kk);
      rB1h = *(const half8*)(gB1h + kk);
      rB0l = *(const half8*)(gB0l + kk);
      rB1l = *(const half8*)(gB1l + kk);
    }
    half8 bh[4], bl[4];
#pragma unroll
    for (int ni = 0; ni < 4; ni++) {
      const int rb = wc * 64 + ni * 16 + l15;
      bh[ni] = *(const half8*)&sB[p][0][rb][soff];
      bl[ni] = *(const half8*)&sB[p][1][rb][soff];
    }
#pragma unroll
    for (int mi = 0; mi < 4; mi++) {
      const int ra = wr * 64 + mi * 16 + l15;
      const half8 ah = *(const half8*)&sA[p][0][ra][soff];
      const half8 al = *(const half8*)&sA[p][1][ra][soff];
#pragma unroll
      for (int ni = 0; ni < 4; ni++) {
        acc[mi][ni] = MFMA16(ah, bh[ni], acc[mi][ni]);
        acc[mi][ni] = MFMA16(ah, bl[ni], acc[mi][ni]);
        acc[mi][ni] = MFMA16(al, bh[ni], acc[mi][ni]);
      }
    }
    if (more) {
      const int q = p ^ 1;
      // reads of buf q ended before the barrier that closed iteration t-1
      *(half8*)&sA[q][0][m0][sp0 * 8] = rA0h;
      *(half8*)&sA[q][0][m1][sp0 * 8] = rA1h;
      *(half8*)&sA[q][1][m0][sp0 * 8] = rA0l;
      *(half8*)&sA[q][1][m1][sp0 * 8] = rA1l;
      *(half8*)&sB[q][0][m0][sp0 * 8] = rB0h;
      *(half8*)&sB[q][0][m1][sp0 * 8] = rB1h;
      *(half8*)&sB[q][1][m0][sp0 * 8] = rB0l;
      *(half8*)&sB[q][1][m1][sp0 * 8] = rB1l;
      __syncthreads();
      p = q;
    }
  }

  // epilogue: C/D layout (verified, dtype-independent): col=lane&15, row=(lane>>4)*4+reg
  const float inv = 1.0f / 8192.0f;
  const int orow = bm + wr * 64 + (lane >> 4) * 4;
  const int ocol = bn + wc * 64 + l15;
#pragma unroll
  for (int ni = 0; ni < 4; ni++) {
    const int col = ocol + ni * 16;
    const float bv = bias[col];
#pragma unroll
    for (int mi = 0; mi < 4; mi++) {
      const f32x4 a = acc[mi][ni];
#pragma unroll
      for (int r = 0; r < 4; r++)
        C[(size_t)(orow + mi * 16 + r) * D_ + col] = a[r] * inv + bv;
    }
  }
}

__global__ __launch_bounds__(256, 2) void gemm_qkv_f16(
    const _Float16* __restrict__ xh, const _Float16* __restrict__ xl,
    const _Float16* __restrict__ Whq, const _Float16* __restrict__ Wlq,
    const _Float16* __restrict__ Whk, const _Float16* __restrict__ Wlk,
    const _Float16* __restrict__ Whv, const _Float16* __restrict__ Wlv,
    const float* __restrict__ bq, const float* __restrict__ bk, const float* __restrict__ bv,
    float* __restrict__ qf, float* __restrict__ kf, float* __restrict__ vf) {
  const int z = blockIdx.z;
  const _Float16* Bh = (z == 0) ? Whq : (z == 1) ? Whk : Whv;
  const _Float16* Bl = (z == 0) ? Wlq : (z == 1) ? Wlk : Wlv;
  const float* bias = (z == 0) ? bq : (z == 1) ? bk : bv;
  float* C = (z == 0) ? qf : (z == 1) ? kf : vf;
  gemm_f16x3_body(xh, xl, Bh, Bl, bias, C);
}

__global__ __launch_bounds__(256, 2) void gemm_out_f16(
    const _Float16* __restrict__ ah, const _Float16* __restrict__ al,
    const _Float16* __restrict__ bh, const _Float16* __restrict__ bl,
    const float* __restrict__ bias, float* __restrict__ C) {
  gemm_f16x3_body(ah, al, bh, bl, bias, C);
}

// ---------------- K transpose, chunk-tiled (unchanged) ----------------
__global__ __launch_bounds__(256) void transpose_k(const float* __restrict__ kf,
                                                   float* __restrict__ kT) {
  __shared__ float tile[64][65];
  const int t = threadIdx.x;
  const int c = blockIdx.x & 15;
  const int h = (blockIdx.x >> 4) & 15;
  const int b = blockIdx.x >> 8;
  const int j0 = c * 64;
  const int jr = t >> 2, ds = (t & 3) * 16;
  const float* src = kf + (size_t)(b * L_ + j0 + jr) * D_ + h * DH_ + ds;
  float4 v0 = ((const float4*)src)[0];
  float4 v1 = ((const float4*)src)[1];
  float4 v2 = ((const float4*)src)[2];
  float4 v3 = ((const float4*)src)[3];
  tile[ds + 0][jr] = v0.x;  tile[ds + 1][jr] = v0.y;  tile[ds + 2][jr] = v0.z;  tile[ds + 3][jr] = v0.w;
  tile[ds + 4][jr] = v1.x;  tile[ds + 5][jr] = v1.y;  tile[ds + 6][jr] = v1.z;  tile[ds + 7][jr] = v1.w;
  tile[ds + 8][jr] = v2.x;  tile[ds + 9][jr] = v2.y;  tile[ds + 10][jr] = v2.z; tile[ds + 11][jr] = v2.w;
  tile[ds + 12][jr] = v3.x; tile[ds + 13][jr] = v3.y; tile[ds + 14][jr] = v3.z; tile[ds + 15][jr] = v3.w;
  __syncthreads();
  const int dr = t >> 2, js = (t & 3) * 16;
  float* dst = kT + ((size_t)((b * 16 + h) * 16 + c)) * 4096 + dr * 64 + js;
  ((float4*)dst)[0] = *(const float4*)&tile[dr][js];
  ((float4*)dst)[1] = *(const float4*)&tile[dr][js + 4];
  ((float4*)dst)[2] = *(const float4*)&tile[dr][js + 8];
  ((float4*)dst)[3] = *(const float4*)&tile[dr][js + 12];
}

// ---------------- attention: unchanged numerics; epilogue now emits fp16 hi/lo ----------------
#define RFL(x) __int_as_float(__builtin_amdgcn_readfirstlane(__float_as_int(x)))
#define LQROW(r) \
  const float q##r##_0  = RFL(qsh[r][qo +  0]), q##r##_1  = RFL(qsh[r][qo +  1]), \
              q##r##_2  = RFL(qsh[r][qo +  2]), q##r##_3  = RFL(qsh[r][qo +  3]), \
              q##r##_4  = RFL(qsh[r][qo +  4]), q##r##_5  = RFL(qsh[r][qo +  5]), \
              q##r##_6  = RFL(qsh[r][qo +  6]), q##r##_7  = RFL(qsh[r][qo +  7]), \
              q##r##_8  = RFL(qsh[r][qo +  8]), q##r##_9  = RFL(qsh[r][qo +  9]), \
              q##r##_10 = RFL(qsh[r][qo + 10]), q##r##_11 = RFL(qsh[r][qo + 11]), \
              q##r##_12 = RFL(qsh[r][qo + 12]), q##r##_13 = RFL(qsh[r][qo + 13]), \
              q##r##_14 = RFL(qsh[r][qo + 14]), q##r##_15 = RFL(qsh[r][qo + 15]);
#define DOT16(r, sacc) \
  sacc = fmaf(kv0,  q##r##_0,  sacc); sacc = fmaf(kv1,  q##r##_1,  sacc); \
  sacc = fmaf(kv2,  q##r##_2,  sacc); sacc = fmaf(kv3,  q##r##_3,  sacc); \
  sacc = fmaf(kv4,  q##r##_4,  sacc); sacc = fmaf(kv5,  q##r##_5,  sacc); \
  sacc = fmaf(kv6,  q##r##_6,  sacc); sacc = fmaf(kv7,  q##r##_7,  sacc); \
  sacc = fmaf(kv8,  q##r##_8,  sacc); sacc = fmaf(kv9,  q##r##_9,  sacc); \
  sacc = fmaf(kv10, q##r##_10, sacc); sacc = fmaf(kv11, q##r##_11, sacc); \
  sacc = fmaf(kv12, q##r##_12, sacc); sacc = fmaf(kv13, q##r##_13, sacc); \
  sacc = fmaf(kv14, q##r##_14, sacc); sacc = fmaf(kv15, q##r##_15, sacc);

__global__ __launch_bounds__(256, 4) void attn_topk_f32(const float* __restrict__ qf,
                                                        const float* __restrict__ kT,
                                                        const float* __restrict__ vf,
                                                        _Float16* __restrict__ awh,
                                                        _Float16* __restrict__ awl) {
  __shared__ float part2[4][4][64][4];   // [c4][row r][j][src wave u]  16 KB
  __shared__ float qsh[4][64];
  const int t = threadIdx.x;
  const int lane = t & 63;
  const int w = t >> 6;
  const int blk = blockIdx.x;
  const int ib = (blk & 255) * 4;
  const int h = (blk >> 8) & 15;
  const int b = blk >> 12;
  const size_t rowbase = (size_t)b * L_;

  { int r = t >> 6, d = t & 63; qsh[r][d] = qf[(rowbase + ib + r) * D_ + h * DH_ + d]; }
  __syncthreads();

  const int qo = 16 * w;
  LQROW(0) LQROW(1) LQROW(2) LQROW(3)

  const float* ktb = kT + ((size_t)(b * 16 + h) * 16) * 4096 + qo * 64;

  float sc[16];
#pragma unroll
  for (int s = 0; s < 4; ++s) {
#pragma unroll
    for (int c4 = 0; c4 < 4; ++c4) {
      const int c = s * 4 + c4;
      const float* kp = ktb + (size_t)c * 4096 + lane;
      const float kv0 = kp[0 * 64],  kv1 = kp[1 * 64],  kv2 = kp[2 * 64],  kv3 = kp[3 * 64],
                  kv4 = kp[4 * 64],  kv5 = kp[5 * 64],  kv6 = kp[6 * 64],  kv7 = kp[7 * 64],
                  kv8 = kp[8 * 64],  kv9 = kp[9 * 64],  kv10 = kp[10 * 64], kv11 = kp[11 * 64],
                  kv12 = kp[12 * 64], kv13 = kp[13 * 64], kv14 = kp[14 * 64], kv15 = kp[15 * 64];
      float p0 = 0.f, p1 = 0.f, p2 = 0.f, p3 = 0.f;
      DOT16(0, p0) DOT16(1, p1) DOT16(2, p2) DOT16(3, p3)
      part2[c4][0][lane][w] = p0;
      part2[c4][1][lane][w] = p1;
      part2[c4][2][lane][w] = p2;
      part2[c4][3][lane][w] = p3;
    }
    __syncthreads();
#pragma unroll
    for (int c4 = 0; c4 < 4; ++c4) {
      float4 p = *(const float4*)&part2[c4][w][lane][0];
      sc[s * 4 + c4] = ((p.x + p.y) + (p.z + p.w)) * 0.125f;
    }
    __syncthreads();
  }

  // ---- max
  float mx = sc[0];
#pragma unroll
  for (int u = 1; u < 16; u++) mx = fmaxf(mx, sc[u]);
#pragma unroll
  for (int off = 32; off >= 1; off >>= 1) mx = fmaxf(mx, __shfl_xor(mx, off, 64));

  // ---- bisection (window mx-16, 14 iters; exact descent below)
  float lo = mx - 16.f, hi = mx;
  for (int it = 0; it < 14; ++it) {
    float mid = 0.5f * (lo + hi);
    int cnt = 0;
#pragma unroll
    for (int u = 0; u < 16; u++) cnt += __popcll(__ballot(sc[u] >= mid));
    if (cnt >= 32) lo = mid; else hi = mid;
  }
  int cabove = 0;
#pragma unroll
  for (int u = 0; u < 16; u++) cabove += __popcll(__ballot(sc[u] >= hi));
  float v31 = hi;
  while (cabove < 32) {
    float nx = -INFINITY;
#pragma unroll
    for (int u = 0; u < 16; u++) nx = fmaxf(nx, (sc[u] < v31) ? sc[u] : -INFINITY);
#pragma unroll
    for (int off = 32; off >= 1; off >>= 1) nx = fmaxf(nx, __shfl_xor(nx, off, 64));
    int ceq = 0;
#pragma unroll
    for (int u = 0; u < 16; u++) ceq += __popcll(__ballot(sc[u] == nx));
    cabove += ceq;
    v31 = nx;
  }
  int c_eq = 0;
#pragma unroll
  for (int u = 0; u < 16; u++) c_eq += __popcll(__ballot(sc[u] == v31));
  const int c_gt = cabove - c_eq;
  const bool span = (cabove > 32);
  const int keep_eq = 32 - c_gt;
  float v32;
  if (span) {
    v32 = v31;
  } else {
    float nx = -INFINITY;
#pragma unroll
    for (int u = 0; u < 16; u++) nx = fmaxf(nx, (sc[u] < v31) ? sc[u] : -INFINITY);
#pragma unroll
    for (int off = 32; off >= 1; off >>= 1) nx = fmaxf(nx, __shfl_xor(nx, off, 64));
    v32 = nx;
  }
  const float tau = 0.5f * (v31 + v32);
  const float invbeta = 166666.67f;   // 1 / 6e-6

  float e[16];
#pragma unroll
  for (int u = 0; u < 16; u++) e[u] = __expf(sc[u] - mx);
  float z = 0.f;
#pragma unroll
  for (int u = 0; u < 16; u++) z += e[u];
#pragma unroll
  for (int off = 32; off >= 1; off >>= 1) z += __shfl_xor(z, off, 64);

  float fw[16];
  if (!span) {
#pragma unroll
    for (int u = 0; u < 16; u++) {
      float arg = (sc[u] - tau) * invbeta;
      fw[u] = (arg > 30.f) ? 1.f : ((arg < -30.f) ? 0.f : 1.f / (1.f + __expf(-arg)));
    }
  }

  const float cutoff = fminf(tau - 1.8e-4f, v31);
  const float* vcol = vf + rowbase * D_ + h * DH_ + lane;
  float S = 0.f, acc = 0.f;
  int eq_seen = 0;
  for (int u = 0; u < 16; ++u) {
    unsigned long long mask = __ballot(sc[u] >= cutoff);
    while (mask) {
      int l2 = (int)__builtin_ctzll(mask);
      mask &= mask - 1;
      float e_ = __shfl(e[u], l2, 64);
      float f_;
      if (span) {
        float s_ = __shfl(sc[u], l2, 64);
        if (s_ > v31) f_ = 1.f;
        else if (s_ == v31) { f_ = (eq_seen < keep_eq) ? 1.f : 0.f; ++eq_seen; }
        else f_ = 0.f;
      } else {
        f_ = __shfl(fw[u], l2, 64);
      }
      float fe = f_ * e_;
      S += fe;
      acc = fmaf(fe, vcol[(size_t)(u * 64 + l2) * D_], acc);
    }
  }
  const float o = acc / (S + 1e-8f * z);
  const float os = o * 16.0f;                    // scale 16 for the f16x3 out-GEMM
  const _Float16 oh = (_Float16)os;
  const size_t oidx = (rowbase + ib + w) * D_ + h * DH_ + lane;
  awh[oidx] = oh;
  awl[oidx] = (_Float16)(os - (float)oh);
}

extern "C" void kernel_launch(void* const* d_in, const int* in_sizes, int n_in,
                              void* d_out, int out_size, void* d_ws, size_t ws_size,
                              hipStream_t stream) {
  const float* x  = (const float*)d_in[0];
  const float* Wq = (const float*)d_in[1];
  const float* bq = (const float*)d_in[2];
  const float* Wk = (const float*)d_in[3];
  const float* bk = (const float*)d_in[4];
  const float* Wv = (const float*)d_in[5];
  const float* bv = (const float*)d_in[6];
  const float* Wo = (const float*)d_in[7];
  const float* bo = (const float*)d_in[8];
  float* out = (float*)d_out;

  const size_t MD = (size_t)M_ * D_;   // 4M floats
  const size_t WD = (size_t)D_ * D_;   // 1M elements
  // ws layout (80 MB, same footprint as before):
  //   [0,16M)   qf (f32)
  //   [16,32M)  kf (f32)           -> after transpose_k: Who/Wlo (f16, 4 MB)
  //   [32,48M)  vf (f32)
  //   [48,64M)  xh/xl (f16, 8+8MB) -> after gemm_qkv: awh/awl (f16)
  //   [64,80M)  Wq/Wk/Wv splits (f16, 12 MB) -> clobbered by kT (f32, 16 MB)
  float* qf = (float*)d_ws;
  float* kf = qf + MD;
  float* vf = kf + MD;
  float* slotA = vf + MD;
  float* kT = slotA + MD;

  _Float16* xh = (_Float16*)slotA;
  _Float16* xl = xh + MD;
  _Float16* awh = xh;                  // alias: xh/xl dead after gemm_qkv
  _Float16* awl = xl;
  _Float16* Whq = (_Float16*)kT;       // dead before transpose_k writes kT
  _Float16* Wlq = Whq + WD;
  _Float16* Whk = Wlq + WD;
  _Float16* Wlk = Whk + WD;
  _Float16* Whv = Wlk + WD;
  _Float16* Wlv = Whv + WD;
  _Float16* Who = (_Float16*)kf;       // written after transpose_k consumes kf
  _Float16* Wlo = Who + WD;

  dim3 b256(256);
  hipLaunchKernelGGL(split_x, dim3(4096), b256, 0, stream, x, xh, xl);
  hipLaunchKernelGGL(split_wt, dim3(256), b256, 0, stream, Wq, Whq, Wlq);
  hipLaunchKernelGGL(split_wt, dim3(256), b256, 0, stream, Wk, Whk, Wlk);
  hipLaunchKernelGGL(split_wt, dim3(256), b256, 0, stream, Wv, Whv, Wlv);
  hipLaunchKernelGGL(gemm_qkv_f16, dim3(8, 32, 3), b256, 0, stream,
                     xh, xl, Whq, Wlq, Whk, Wlk, Whv, Wlv, bq, bk, bv, qf, kf, vf);
  hipLaunchKernelGGL(transpose_k, dim3(1024), b256, 0, stream, kf, kT);
  hipLaunchKernelGGL(split_wt, dim3(256), b256, 0, stream, Wo, Who, Wlo);
  hipLaunchKernelGGL(attn_topk_f32, dim3(16384), b256, 0, stream, qf, kT, vf, awh, awl);
  hipLaunchKernelGGL(gemm_out_f16, dim3(8, 32), b256, 0, stream, awh, awl, Who, Wlo, bo, out);
}